// Round 6
// baseline (450.032 us; speedup 1.0000x reference)
//
#include <hip/hip_runtime.h>

// Problem constants
#define NB   64
#define NR   50
#define LTOK 15
#define DIM  1024      // D (pooling dim), output per-half width
#define FEAT 4096      // F (K of the GEMM)
#define MTOT (NB*NR)   // 3200 rows
#define OSTRIDE (2*DIM)

typedef __attribute__((ext_vector_type(8))) short bf16x8;  // 8 bf16 = 4 VGPRs
typedef __attribute__((ext_vector_type(4))) float f32x4;   // MFMA C/D frag

// ---- workspace layout (bytes) ----
#define WS_AH 0ull
#define WS_AL 26214400ull            // 3200*4096*2
#define WS_BH 52428800ull
#define WS_BL 60817408ull            // + 1024*4096*2
#define WS_PB 69206016ull            // partials: 4 x 3200 x 1024 f32
#define WS_NEED 121634816ull

#define KS_PER_SPLIT 96              // k-steps of 32 per split (384 total / 4)
#define TOTAL_BLOCKS 4160            // 832 gemm slots (1-in-5) + mp slots

// global_load_lds, 16B/lane; LDS dest = wave-uniform base + lane*16 (m97).
#define GLOAD16(gsrc, ldst)                                                   \
    __builtin_amdgcn_global_load_lds(                                         \
        (__attribute__((address_space(1))) void*)(gsrc),                      \
        (__attribute__((address_space(3))) void*)(ldst), 16, 0, 0)

// ---------------------------------------------------------------------------
// Kernel 1: one-time exact hi/lo bf16 split of A (features) and W into ws.
// Truncation split: h = top16(x); l = top16(x - h).  x = h + l + O(2^-16 x).
// ---------------------------------------------------------------------------
__device__ __forceinline__ void split_trunc(float x, unsigned short& h, unsigned short& l) {
    unsigned int u = __builtin_bit_cast(unsigned int, x);
    h = (unsigned short)(u >> 16);
    float r = x - __builtin_bit_cast(float, u & 0xffff0000u);
    l = (unsigned short)(__builtin_bit_cast(unsigned int, r) >> 16);
}

__global__ __launch_bounds__(256) void split_kernel(
    const float* __restrict__ A, const float* __restrict__ W,
    unsigned short* __restrict__ Ah, unsigned short* __restrict__ Al,
    unsigned short* __restrict__ Bh, unsigned short* __restrict__ Bl)
{
    const int NA4 = MTOT * FEAT / 4;
    const int NW4 = DIM * FEAT / 4;
    for (int i = blockIdx.x * 256 + threadIdx.x; i < NA4 + NW4;
         i += gridDim.x * 256) {
        const bool isA = i < NA4;
        const int  j   = isA ? i : i - NA4;
        const float4 v = isA ? reinterpret_cast<const float4*>(A)[j]
                             : reinterpret_cast<const float4*>(W)[j];
        ushort4 h, l;
        split_trunc(v.x, h.x, l.x); split_trunc(v.y, h.y, l.y);
        split_trunc(v.z, h.z, l.z); split_trunc(v.w, h.w, l.w);
        if (isA) {
            reinterpret_cast<ushort4*>(Ah)[j] = h;
            reinterpret_cast<ushort4*>(Al)[j] = l;
        } else {
            reinterpret_cast<ushort4*>(Bh)[j] = h;
            reinterpret_cast<ushort4*>(Bl)[j] = l;
        }
    }
}

// ---------------------------------------------------------------------------
// Kernel 2 (fused): 1-in-5 blocks = GEMM partials (bf16 MFMA, split-K=4,
// 3-phase split-bf16: Ah.Bh | Al.Bh | Ah.Bl); 4-in-5 = mean-pool rows
// (interleaved so phrase streaming overlaps GEMM compute).
//
// GEMM: 128x128 tile, BK=32, 4 waves, wave-tile 64x64 (16 MFMA : 8 ds_read).
// T4 counted-vmcnt 3-buffer pipeline: per step {s_waitcnt vmcnt(4);
// s_barrier; stage(i+2); ds_read frags(buf i); 16 MFMA}. Ledger: at step-i
// top, issued stages 0..i+1 (4 loads each); vmcnt(4) retires all but
// stage(i+1) => stage(i) LDS-resident for ALL waves after the barrier;
// stage(i+2) overwrites buf (i-1)%3 whose reads finished before barrier i.
// vmcnt never drains to 0 in the loop (the round-5 stall).
//
// XCD co-location: the 8 nt-blocks of one (mt,q) group share g%8 ==> same
// bid%8 ==> same XCD; the A-slice is fetched into that L2 once, not 8x HBM.
// ---------------------------------------------------------------------------
__global__ __launch_bounds__(256, 3) void gemm_mp_kernel(
    const unsigned short* __restrict__ Ah, const unsigned short* __restrict__ Al,
    const unsigned short* __restrict__ Bh, const unsigned short* __restrict__ Bl,
    const float* __restrict__ phrases, const int* __restrict__ lengths,
    float* __restrict__ pbuf, float* __restrict__ out)
{
    const int bid = blockIdx.x;

    if (bid % 5 != 0) {
        // ---------------- mean-pool path (1 row per block) ----------------
        const int br = bid - bid / 5 - 1;                 // 0..3327
        if (br >= MTOT) return;
        const int len = lengths[br];                      // wave-uniform
        const int d4  = threadIdx.x;                      // 0..255
        const float4* p = reinterpret_cast<const float4*>(
            phrases + (size_t)br * LTOK * DIM) + d4;
        float4 acc = make_float4(0.f, 0.f, 0.f, 0.f);
        #pragma unroll 3
        for (int l = 0; l < len; ++l) {                   // skip zero padding
            float4 v = p[(size_t)l * (DIM / 4)];
            acc.x += v.x; acc.y += v.y; acc.z += v.z; acc.w += v.w;
        }
        const float inv = 1.0f / (float)len;
        acc.x *= inv; acc.y *= inv; acc.z *= inv; acc.w *= inv;
        reinterpret_cast<float4*>(out + (size_t)br * OSTRIDE + DIM)[d4] = acc;
        return;
    }

    // ------------------------------ GEMM path ------------------------------
    // decode g -> (group G=(q,mt), nt) with G%8 == g%8 (XCD co-location)
    const int g   = bid / 5;             // 0..831
    const int s8  = g >> 6;              // super-row (8 groups each)
    const int rem = g & 63;
    const int nt  = rem >> 3;            // n-tile 0..7
    const int G   = s8 * 8 + (rem & 7);  // group id
    if (G >= 100) return;                // 832 slots, 800 real
    const int q   = G / 25;              // k-split 0..3
    const int mt  = G % 25;              // m-tile

    __shared__ unsigned short At[3][128][32];
    __shared__ unsigned short Bt[3][128][32];

    const int tid  = threadIdx.x;
    const int lane = tid & 63;
    const int w    = tid >> 6;
    const int wr   = (w >> 1) * 64;      // wave-tile M offset
    const int wc   = (w & 1) * 64;       // wave-tile N offset
    const int fr   = lane & 15;
    const int fk   = (lane >> 4) * 8;

    // staging geometry: wave w fills 16-row chunks c0, c0+1 of both tiles
    const int c0    = w * 2;
    const int srow  = lane >> 2;
    const int skoff = (lane & 3) * 8;
    const unsigned aoff0 = (unsigned)(mt * 128 + 16 * c0      + srow) * FEAT + skoff;
    const unsigned aoff1 = (unsigned)(mt * 128 + 16 * (c0+1)  + srow) * FEAT + skoff;
    const unsigned boff0 = (unsigned)(nt * 128 + 16 * c0      + srow) * FEAT + skoff;
    const unsigned boff1 = (unsigned)(nt * 128 + 16 * (c0+1)  + srow) * FEAT + skoff;

    auto stage = [&](int buf, int s) {
        // phase select: [0,128)=Ah.Bh  [128,256)=Al.Bh  [256,384)=Ah.Bl
        // s may overshoot 383 in the tail: (s&127) wraps, selects Ah/Bl,
        // addresses stay in-bounds; the loads land in a buffer never read.
        const unsigned short* aS = (s < 128) ? Ah : (s < 256 ? Al : Ah);
        const unsigned short* bS = (s < 256) ? Bh : Bl;
        const unsigned kk = (unsigned)(s & 127) * 32;
        GLOAD16(aS + aoff0 + kk, &At[buf][16 * c0][0]);
        GLOAD16(aS + aoff1 + kk, &At[buf][16 * c0 + 16][0]);
        GLOAD16(bS + boff0 + kk, &Bt[buf][16 * c0][0]);
        GLOAD16(bS + boff1 + kk, &Bt[buf][16 * c0 + 16][0]);
    };

    f32x4 acc[4][4] = {};
    const int s0 = q * KS_PER_SPLIT;

    stage(0, s0);                        // prologue: 8 loads in flight
    stage(1, s0 + 1);

    for (int i = 0; i < KS_PER_SPLIT; ++i) {
        // my stage(i) done (only stage(i+1)'s 4 loads may remain in flight)
        asm volatile("s_waitcnt vmcnt(4)" ::: "memory");
        // all waves' stage(i) writes visible; all reads of buf (i-1)%3 done
        __builtin_amdgcn_s_barrier();

        stage((i + 2) % 3, s0 + i + 2);  // refill; never read past the tail

        const int buf = i % 3;
        bf16x8 a[4], b[4];
        #pragma unroll
        for (int m = 0; m < 4; ++m)
            a[m] = *reinterpret_cast<const bf16x8*>(&At[buf][wr + m * 16 + fr][fk]);
        #pragma unroll
        for (int n = 0; n < 4; ++n)
            b[n] = *reinterpret_cast<const bf16x8*>(&Bt[buf][wc + n * 16 + fr][fk]);

        #pragma unroll
        for (int m = 0; m < 4; ++m)
            #pragma unroll
            for (int n = 0; n < 4; ++n)
                acc[m][n] = __builtin_amdgcn_mfma_f32_16x16x32_bf16(
                    a[m], b[n], acc[m][n], 0, 0, 0);
    }

    asm volatile("s_waitcnt vmcnt(0)" ::: "memory");   // drain tail loads

    // partial store: pbuf[q][row][col]  (C/D: col=lane&15, row=(lane>>4)*4+r)
    const int prow0 = mt * 128 + wr + (lane >> 4) * 4;
    const int pcol0 = nt * 128 + wc + fr;
    float* pq = pbuf + (size_t)q * MTOT * DIM;
    #pragma unroll
    for (int m = 0; m < 4; ++m)
        #pragma unroll
        for (int n = 0; n < 4; ++n)
            #pragma unroll
            for (int r = 0; r < 4; ++r)
                pq[(size_t)(prow0 + m * 16 + r) * DIM + (pcol0 + n * 16)] =
                    acc[m][n][r];
}

// ---------------------------------------------------------------------------
// Kernel 3: vis = relu(sum_q pbuf[q] + bias) -> out[:, 0:D). One row/block.
// ---------------------------------------------------------------------------
__global__ __launch_bounds__(256) void epi_kernel(
    const float* __restrict__ pbuf, const float* __restrict__ bias,
    float* __restrict__ out)
{
    const int r = blockIdx.x;
    const int j = threadIdx.x;
    const size_t qs = (size_t)MTOT * (DIM / 4);
    const float4* p = reinterpret_cast<const float4*>(pbuf) + (size_t)r * (DIM / 4) + j;
    float4 s0 = p[0], s1 = p[qs], s2 = p[2 * qs], s3 = p[3 * qs];
    const float4 bv = reinterpret_cast<const float4*>(bias)[j];
    float4 v;
    v.x = fmaxf(s0.x + s1.x + s2.x + s3.x + bv.x, 0.f);
    v.y = fmaxf(s0.y + s1.y + s2.y + s3.y + bv.y, 0.f);
    v.z = fmaxf(s0.z + s1.z + s2.z + s3.z + bv.z, 0.f);
    v.w = fmaxf(s0.w + s1.w + s2.w + s3.w + bv.w, 0.f);
    reinterpret_cast<float4*>(out + (size_t)r * OSTRIDE)[j] = v;
}

// ===========================================================================
// FALLBACK path (ws too small): round-3 verified kernels, unchanged.
// ===========================================================================
__global__ __launch_bounds__(256) void mean_pool_kernel(
    const float* __restrict__ phrases, const int* __restrict__ lengths,
    float* __restrict__ out)
{
    const int br = blockIdx.x;
    const int d4 = threadIdx.x;
    const float4* p = reinterpret_cast<const float4*>(
        phrases + (size_t)br * LTOK * DIM) + d4;
    float4 acc = make_float4(0.f, 0.f, 0.f, 0.f);
    #pragma unroll
    for (int l = 0; l < LTOK; ++l) {
        float4 v = p[(size_t)l * (DIM / 4)];
        acc.x += v.x; acc.y += v.y; acc.z += v.z; acc.w += v.w;
    }
    const float inv = 1.0f / (float)lengths[br];
    acc.x *= inv; acc.y *= inv; acc.z *= inv; acc.w *= inv;
    reinterpret_cast<float4*>(out + (size_t)br * OSTRIDE + DIM)[d4] = acc;
}

#define BM 128
#define BN 128
#define BK 32
#define LDSP 40

__device__ __forceinline__ unsigned short bf16_rne(float f) {
    unsigned int u = __builtin_bit_cast(unsigned int, f);
    unsigned int r = (u + 0x7fffu + ((u >> 16) & 1u)) >> 16;
    return (unsigned short)r;
}
__device__ __forceinline__ float bf16_to_f(unsigned short h) {
    return __builtin_bit_cast(float, (unsigned int)h << 16);
}
__device__ __forceinline__ void split4(const float4 v, ushort4& h, ushort4& l) {
    h.x = bf16_rne(v.x); l.x = bf16_rne(v.x - bf16_to_f(h.x));
    h.y = bf16_rne(v.y); l.y = bf16_rne(v.y - bf16_to_f(h.y));
    h.z = bf16_rne(v.z); l.z = bf16_rne(v.z - bf16_to_f(h.z));
    h.w = bf16_rne(v.w); l.w = bf16_rne(v.w - bf16_to_f(h.w));
}

__global__ __launch_bounds__(256, 1) void gemm_relu_mfma(
    const float* __restrict__ A, const float* __restrict__ Bw,
    const float* __restrict__ bias, float* __restrict__ out)
{
    __shared__ __align__(16) unsigned short AhS[BM][LDSP];
    __shared__ __align__(16) unsigned short AlS[BM][LDSP];
    __shared__ __align__(16) unsigned short BhS[BN][LDSP];
    __shared__ __align__(16) unsigned short BlS[BN][LDSP];

    const int tid = threadIdx.x;
    const int m0  = blockIdx.y * BM;
    const int n0  = blockIdx.x * BN;
    const int srow = tid >> 3;
    const int scol = (tid & 7) * 4;
    const float* Aptr = A  + (size_t)(m0 + srow) * FEAT + scol;
    const float* Bptr = Bw + (size_t)(n0 + srow) * FEAT + scol;
    const int lane = tid & 63;
    const int wr   = ((tid >> 6) >> 1) * 64;
    const int wc   = ((tid >> 6) & 1) * 64;
    const int fr   = lane & 15;
    const int fk   = (lane >> 4) * 8;

    f32x4 acc[4][4] = {};
    float4 pa[4], pb[4];
    #pragma unroll
    for (int p = 0; p < 4; ++p) {
        pa[p] = *reinterpret_cast<const float4*>(Aptr + (size_t)(p * 32) * FEAT);
        pb[p] = *reinterpret_cast<const float4*>(Bptr + (size_t)(p * 32) * FEAT);
    }
    const int NK = FEAT / BK;
    for (int kt = 0; kt < NK; ++kt) {
        __syncthreads();
        #pragma unroll
        for (int p = 0; p < 4; ++p) {
            const int r = srow + p * 32;
            ushort4 h, l;
            split4(pa[p], h, l);
            *reinterpret_cast<ushort4*>(&AhS[r][scol]) = h;
            *reinterpret_cast<ushort4*>(&AlS[r][scol]) = l;
            split4(pb[p], h, l);
            *reinterpret_cast<ushort4*>(&BhS[r][scol]) = h;
            *reinterpret_cast<ushort4*>(&BlS[r][scol]) = l;
        }
        __syncthreads();
        if (kt + 1 < NK) {
            const float* An = Aptr + (size_t)(kt + 1) * BK;
            const float* Bn = Bptr + (size_t)(kt + 1) * BK;
            #pragma unroll
            for (int p = 0; p < 4; ++p) {
                pa[p] = *reinterpret_cast<const float4*>(An + (size_t)(p * 32) * FEAT);
                pb[p] = *reinterpret_cast<const float4*>(Bn + (size_t)(p * 32) * FEAT);
            }
        }
        bf16x8 fah[4], fal[4], fbh[4], fbl[4];
        #pragma unroll
        for (int m = 0; m < 4; ++m) {
            fah[m] = *reinterpret_cast<const bf16x8*>(&AhS[wr + m * 16 + fr][fk]);
            fal[m] = *reinterpret_cast<const bf16x8*>(&AlS[wr + m * 16 + fr][fk]);
        }
        #pragma unroll
        for (int n = 0; n < 4; ++n) {
            fbh[n] = *reinterpret_cast<const bf16x8*>(&BhS[wc + n * 16 + fr][fk]);
            fbl[n] = *reinterpret_cast<const bf16x8*>(&BlS[wc + n * 16 + fr][fk]);
        }
        #pragma unroll
        for (int m = 0; m < 4; ++m)
            #pragma unroll
            for (int n = 0; n < 4; ++n) {
                acc[m][n] = __builtin_amdgcn_mfma_f32_16x16x32_bf16(fah[m], fbl[n], acc[m][n], 0, 0, 0);
                acc[m][n] = __builtin_amdgcn_mfma_f32_16x16x32_bf16(fal[m], fbh[n], acc[m][n], 0, 0, 0);
                acc[m][n] = __builtin_amdgcn_mfma_f32_16x16x32_bf16(fah[m], fbh[n], acc[m][n], 0, 0, 0);
            }
    }
    const int orow0 = m0 + wr + (lane >> 4) * 4;
    const int ocol0 = n0 + wc + fr;
    #pragma unroll
    for (int n = 0; n < 4; ++n) {
        const float bv = bias[ocol0 + n * 16];
        #pragma unroll
        for (int m = 0; m < 4; ++m)
            #pragma unroll
            for (int r = 0; r < 4; ++r) {
                float v = acc[m][n][r] + bv;
                out[(size_t)(orow0 + m * 16 + r) * OSTRIDE + (ocol0 + n * 16)] =
                    fmaxf(v, 0.f);
            }
    }
}

// ---------------------------------------------------------------------------
// Inputs: d_in[0] features f32, [1] phrases f32, [2] W f32, [3] b f32,
//         [4] phrase_lengths i32.  Output [B,R,2D] f32.
// ---------------------------------------------------------------------------
extern "C" void kernel_launch(void* const* d_in, const int* in_sizes, int n_in,
                              void* d_out, int out_size, void* d_ws, size_t ws_size,
                              hipStream_t stream) {
    const float* features = (const float*)d_in[0];
    const float* phrases  = (const float*)d_in[1];
    const float* W        = (const float*)d_in[2];
    const float* bias     = (const float*)d_in[3];
    const int*   lengths  = (const int*)d_in[4];
    float* out = (float*)d_out;

    if (ws_size >= WS_NEED) {
        char* ws = (char*)d_ws;
        unsigned short* Ah = (unsigned short*)(ws + WS_AH);
        unsigned short* Al = (unsigned short*)(ws + WS_AL);
        unsigned short* Bh = (unsigned short*)(ws + WS_BH);
        unsigned short* Bl = (unsigned short*)(ws + WS_BL);
        float* pbuf = (float*)(ws + WS_PB);

        split_kernel<<<dim3(2048), dim3(256), 0, stream>>>(
            features, W, Ah, Al, Bh, Bl);
        gemm_mp_kernel<<<dim3(TOTAL_BLOCKS), dim3(256), 0, stream>>>(
            Ah, Al, Bh, Bl, phrases, lengths, pbuf, out);
        epi_kernel<<<dim3(MTOT), dim3(256), 0, stream>>>(pbuf, bias, out);
    } else {
        // ws too small: round-3 verified path
        mean_pool_kernel<<<dim3(MTOT), dim3(256), 0, stream>>>(phrases, lengths, out);
        gemm_relu_mfma<<<dim3(DIM / BN, MTOT / BM), dim3(256), 0, stream>>>(
            features, W, bias, out);
    }
}

// Round 7
// 446.909 us; speedup vs baseline: 1.0070x; 1.0070x over previous
//
#include <hip/hip_runtime.h>

// Problem constants
#define NB   64
#define NR   50
#define LTOK 15
#define DIM  1024      // D (pooling dim), output per-half width
#define FEAT 4096      // F (K of the GEMM)
#define MTOT (NB*NR)   // 3200 rows
#define OSTRIDE (2*DIM)

typedef __attribute__((ext_vector_type(8))) short bf16x8;  // 8 bf16 = 4 VGPRs
typedef __attribute__((ext_vector_type(4))) float f32x4;   // MFMA C/D frag

// ---- workspace layout (bytes) ----
#define WS_AH 0ull
#define WS_AL 26214400ull            // 3200*4096*2
#define WS_BH 52428800ull
#define WS_BL 60817408ull            // + 1024*4096*2
#define WS_PB 69206016ull            // partials: 4 x 3200 x 1024 f32
#define WS_NEED 121634816ull

#define KS_PER_SPLIT 96              // k-steps of 32 per split (384 total / 4)
#define GEMM_SLOTS 832               // 13 super-rows x 64 (800 real, 32 idle)
#define TOTAL_BLOCKS (GEMM_SLOTS + MTOT)

// global_load_lds, 16B/lane; LDS dest = wave-uniform base + lane*16 (m97).
#define GLOAD16(gsrc, ldst)                                                   \
    __builtin_amdgcn_global_load_lds(                                         \
        (__attribute__((address_space(1))) void*)(gsrc),                      \
        (__attribute__((address_space(3))) void*)(ldst), 16, 0, 0)

// ---------------------------------------------------------------------------
// Kernel 1: one-time exact hi/lo bf16 split of A (features) and W into ws.
// Truncation split: h = top16(x); l = top16(x - h).  x = h + l + O(2^-16 x).
// ---------------------------------------------------------------------------
__device__ __forceinline__ void split_trunc(float x, unsigned short& h, unsigned short& l) {
    unsigned int u = __builtin_bit_cast(unsigned int, x);
    h = (unsigned short)(u >> 16);
    float r = x - __builtin_bit_cast(float, u & 0xffff0000u);
    l = (unsigned short)(__builtin_bit_cast(unsigned int, r) >> 16);
}

__global__ __launch_bounds__(256) void split_kernel(
    const float* __restrict__ A, const float* __restrict__ W,
    unsigned short* __restrict__ Ah, unsigned short* __restrict__ Al,
    unsigned short* __restrict__ Bh, unsigned short* __restrict__ Bl)
{
    const int NA4 = MTOT * FEAT / 4;
    const int NW4 = DIM * FEAT / 4;
    for (int i = blockIdx.x * 256 + threadIdx.x; i < NA4 + NW4;
         i += gridDim.x * 256) {
        const bool isA = i < NA4;
        const int  j   = isA ? i : i - NA4;
        const float4 v = isA ? reinterpret_cast<const float4*>(A)[j]
                             : reinterpret_cast<const float4*>(W)[j];
        ushort4 h, l;
        split_trunc(v.x, h.x, l.x); split_trunc(v.y, h.y, l.y);
        split_trunc(v.z, h.z, l.z); split_trunc(v.w, h.w, l.w);
        if (isA) {
            reinterpret_cast<ushort4*>(Ah)[j] = h;
            reinterpret_cast<ushort4*>(Al)[j] = l;
        } else {
            reinterpret_cast<ushort4*>(Bh)[j] = h;
            reinterpret_cast<ushort4*>(Bl)[j] = l;
        }
    }
}

// ---------------------------------------------------------------------------
// Kernel 2 (fused): blocks [0,832) = GEMM partials (bf16 MFMA, split-K=4,
// 3-phase split-bf16: Ah.Bh | Al.Bh | Ah.Bl); blocks [832, 832+3200) =
// mean-pool rows (dispatched AFTER all gemm blocks -> gemm gets clean BW
// during fill; mp streams under the gemm tail).  [r6 lesson: interleaving
// mp 4-in-5 contended every stage load -> reverted to r5 ordering.]
//
// GEMM: 128x128 tile, BK=32, 4 waves, wave-tile 64x64 (16 MFMA : 8 ds_read).
// T4 DEEP pipeline: 4 LDS buffers (64 KB -> 2 blocks/CU), 3 stages in
// flight.  Per step: {s_waitcnt vmcnt(8) [stage i resident, i+1/i+2 in
// flight]; s_barrier; stage(i+3) into buf (i+3)%4 [reads finished step
// i-1]; ds_read frags buf i%4; 16 MFMA}.  vmcnt floor in loop = 8; ~3
// step-times of load slack covers L2-hit latency.  2 blocks/CU cover each
// other's vmcnt waits.
//
// XCD co-location: all 8 nt-blocks of one group G=(q,mt) share bid%8 ==
// same XCD; the A-slice is fetched into that L2 once, not 8x from HBM.
// ---------------------------------------------------------------------------
__global__ __launch_bounds__(256, 2) void gemm_mp_kernel(
    const unsigned short* __restrict__ Ah, const unsigned short* __restrict__ Al,
    const unsigned short* __restrict__ Bh, const unsigned short* __restrict__ Bl,
    const float* __restrict__ phrases, const int* __restrict__ lengths,
    float* __restrict__ pbuf, float* __restrict__ out)
{
    const int bid = blockIdx.x;

    if (bid >= GEMM_SLOTS) {
        // ---------------- mean-pool path (1 row per block) ----------------
        const int br = bid - GEMM_SLOTS;                  // 0..3199
        const int len = lengths[br];                      // wave-uniform
        const int d4  = threadIdx.x;                      // 0..255
        const float4* p = reinterpret_cast<const float4*>(
            phrases + (size_t)br * LTOK * DIM) + d4;
        float4 acc = make_float4(0.f, 0.f, 0.f, 0.f);
        #pragma unroll 3
        for (int l = 0; l < len; ++l) {                   // skip zero padding
            float4 v = p[(size_t)l * (DIM / 4)];
            acc.x += v.x; acc.y += v.y; acc.z += v.z; acc.w += v.w;
        }
        const float inv = 1.0f / (float)len;
        acc.x *= inv; acc.y *= inv; acc.z *= inv; acc.w *= inv;
        reinterpret_cast<float4*>(out + (size_t)br * OSTRIDE + DIM)[d4] = acc;
        return;
    }

    // ------------------------------ GEMM path ------------------------------
    // decode bid -> (group G=(q,mt), nt) with G%8 == bid%8 (XCD co-location)
    const int g   = bid;                 // 0..831
    const int s8  = g >> 6;              // super-row (8 groups each)
    const int rem = g & 63;
    const int nt  = rem >> 3;            // n-tile 0..7
    const int G   = s8 * 8 + (rem & 7);  // group id 0..103
    if (G >= 100) return;                // 832 slots, 800 real
    const int q   = G / 25;              // k-split 0..3
    const int mt  = G % 25;              // m-tile

    __shared__ unsigned short At[4][128][32];
    __shared__ unsigned short Bt[4][128][32];

    const int tid  = threadIdx.x;
    const int lane = tid & 63;
    const int w    = tid >> 6;
    const int wr   = (w >> 1) * 64;      // wave-tile M offset
    const int wc   = (w & 1) * 64;       // wave-tile N offset
    const int fr   = lane & 15;
    const int fk   = (lane >> 4) * 8;

    // staging geometry: wave w fills 16-row chunks c0, c0+1 of both tiles
    const int c0    = w * 2;
    const int srow  = lane >> 2;
    const int skoff = (lane & 3) * 8;
    const unsigned aoff0 = (unsigned)(mt * 128 + 16 * c0      + srow) * FEAT + skoff;
    const unsigned aoff1 = (unsigned)(mt * 128 + 16 * (c0+1)  + srow) * FEAT + skoff;
    const unsigned boff0 = (unsigned)(nt * 128 + 16 * c0      + srow) * FEAT + skoff;
    const unsigned boff1 = (unsigned)(nt * 128 + 16 * (c0+1)  + srow) * FEAT + skoff;

    auto stage = [&](int buf, int s) {
        // phase select: [0,128)=Ah.Bh  [128,256)=Al.Bh  [256,384)=Ah.Bl
        // s may overshoot 383 in the tail: (s&127) wraps, selects Ah/Bl,
        // addresses stay in-bounds; the loads land in a buffer never read.
        const unsigned short* aS = (s < 128) ? Ah : (s < 256 ? Al : Ah);
        const unsigned short* bS = (s < 256) ? Bh : Bl;
        const unsigned kk = (unsigned)(s & 127) * 32;
        GLOAD16(aS + aoff0 + kk, &At[buf][16 * c0][0]);
        GLOAD16(aS + aoff1 + kk, &At[buf][16 * c0 + 16][0]);
        GLOAD16(bS + boff0 + kk, &Bt[buf][16 * c0][0]);
        GLOAD16(bS + boff1 + kk, &Bt[buf][16 * c0 + 16][0]);
    };

    f32x4 acc[4][4] = {};
    const int s0 = q * KS_PER_SPLIT;

    stage(0, s0);                        // prologue: 12 loads in flight
    stage(1, s0 + 1);
    stage(2, s0 + 2);

    for (int i = 0; i < KS_PER_SPLIT; ++i) {
        // retire my stage(i) (stages i+1, i+2 = 8 loads may remain in flight)
        asm volatile("s_waitcnt vmcnt(8)" ::: "memory");
        // all waves' stage(i) writes visible; all reads of buf (i+3)%4
        // (done at step i-1) are complete across the block
        __builtin_amdgcn_s_barrier();

        stage((i + 3) & 3, s0 + i + 3);  // refill 3 ahead

        const int buf = i & 3;
        bf16x8 a[4], b[4];
        #pragma unroll
        for (int m = 0; m < 4; ++m)
            a[m] = *reinterpret_cast<const bf16x8*>(&At[buf][wr + m * 16 + fr][fk]);
        #pragma unroll
        for (int n = 0; n < 4; ++n)
            b[n] = *reinterpret_cast<const bf16x8*>(&Bt[buf][wc + n * 16 + fr][fk]);

        #pragma unroll
        for (int m = 0; m < 4; ++m)
            #pragma unroll
            for (int n = 0; n < 4; ++n)
                acc[m][n] = __builtin_amdgcn_mfma_f32_16x16x32_bf16(
                    a[m], b[n], acc[m][n], 0, 0, 0);
    }

    asm volatile("s_waitcnt vmcnt(0)" ::: "memory");   // drain tail loads

    // partial store: pbuf[q][row][col]  (C/D: col=lane&15, row=(lane>>4)*4+r)
    const int prow0 = mt * 128 + wr + (lane >> 4) * 4;
    const int pcol0 = nt * 128 + wc + fr;
    float* pq = pbuf + (size_t)q * MTOT * DIM;
    #pragma unroll
    for (int m = 0; m < 4; ++m)
        #pragma unroll
        for (int n = 0; n < 4; ++n)
            #pragma unroll
            for (int r = 0; r < 4; ++r)
                pq[(size_t)(prow0 + m * 16 + r) * DIM + (pcol0 + n * 16)] =
                    acc[m][n][r];
}

// ---------------------------------------------------------------------------
// Kernel 3: vis = relu(sum_q pbuf[q] + bias) -> out[:, 0:D). One row/block.
// ---------------------------------------------------------------------------
__global__ __launch_bounds__(256) void epi_kernel(
    const float* __restrict__ pbuf, const float* __restrict__ bias,
    float* __restrict__ out)
{
    const int r = blockIdx.x;
    const int j = threadIdx.x;
    const size_t qs = (size_t)MTOT * (DIM / 4);
    const float4* p = reinterpret_cast<const float4*>(pbuf) + (size_t)r * (DIM / 4) + j;
    float4 s0 = p[0], s1 = p[qs], s2 = p[2 * qs], s3 = p[3 * qs];
    const float4 bv = reinterpret_cast<const float4*>(bias)[j];
    float4 v;
    v.x = fmaxf(s0.x + s1.x + s2.x + s3.x + bv.x, 0.f);
    v.y = fmaxf(s0.y + s1.y + s2.y + s3.y + bv.y, 0.f);
    v.z = fmaxf(s0.z + s1.z + s2.z + s3.z + bv.z, 0.f);
    v.w = fmaxf(s0.w + s1.w + s2.w + s3.w + bv.w, 0.f);
    reinterpret_cast<float4*>(out + (size_t)r * OSTRIDE)[j] = v;
}

// ===========================================================================
// FALLBACK path (ws too small): round-3 verified kernels, unchanged.
// ===========================================================================
__global__ __launch_bounds__(256) void mean_pool_kernel(
    const float* __restrict__ phrases, const int* __restrict__ lengths,
    float* __restrict__ out)
{
    const int br = blockIdx.x;
    const int d4 = threadIdx.x;
    const float4* p = reinterpret_cast<const float4*>(
        phrases + (size_t)br * LTOK * DIM) + d4;
    float4 acc = make_float4(0.f, 0.f, 0.f, 0.f);
    #pragma unroll
    for (int l = 0; l < LTOK; ++l) {
        float4 v = p[(size_t)l * (DIM / 4)];
        acc.x += v.x; acc.y += v.y; acc.z += v.z; acc.w += v.w;
    }
    const float inv = 1.0f / (float)lengths[br];
    acc.x *= inv; acc.y *= inv; acc.z *= inv; acc.w *= inv;
    reinterpret_cast<float4*>(out + (size_t)br * OSTRIDE + DIM)[d4] = acc;
}

#define BM 128
#define BN 128
#define BK 32
#define LDSP 40

__device__ __forceinline__ unsigned short bf16_rne(float f) {
    unsigned int u = __builtin_bit_cast(unsigned int, f);
    unsigned int r = (u + 0x7fffu + ((u >> 16) & 1u)) >> 16;
    return (unsigned short)r;
}
__device__ __forceinline__ float bf16_to_f(unsigned short h) {
    return __builtin_bit_cast(float, (unsigned int)h << 16);
}
__device__ __forceinline__ void split4(const float4 v, ushort4& h, ushort4& l) {
    h.x = bf16_rne(v.x); l.x = bf16_rne(v.x - bf16_to_f(h.x));
    h.y = bf16_rne(v.y); l.y = bf16_rne(v.y - bf16_to_f(h.y));
    h.z = bf16_rne(v.z); l.z = bf16_rne(v.z - bf16_to_f(h.z));
    h.w = bf16_rne(v.w); l.w = bf16_rne(v.w - bf16_to_f(h.w));
}

__global__ __launch_bounds__(256, 1) void gemm_relu_mfma(
    const float* __restrict__ A, const float* __restrict__ Bw,
    const float* __restrict__ bias, float* __restrict__ out)
{
    __shared__ __align__(16) unsigned short AhS[BM][LDSP];
    __shared__ __align__(16) unsigned short AlS[BM][LDSP];
    __shared__ __align__(16) unsigned short BhS[BN][LDSP];
    __shared__ __align__(16) unsigned short BlS[BN][LDSP];

    const int tid = threadIdx.x;
    const int m0  = blockIdx.y * BM;
    const int n0  = blockIdx.x * BN;
    const int srow = tid >> 3;
    const int scol = (tid & 7) * 4;
    const float* Aptr = A  + (size_t)(m0 + srow) * FEAT + scol;
    const float* Bptr = Bw + (size_t)(n0 + srow) * FEAT + scol;
    const int lane = tid & 63;
    const int wr   = ((tid >> 6) >> 1) * 64;
    const int wc   = ((tid >> 6) & 1) * 64;
    const int fr   = lane & 15;
    const int fk   = (lane >> 4) * 8;

    f32x4 acc[4][4] = {};
    float4 pa[4], pb[4];
    #pragma unroll
    for (int p = 0; p < 4; ++p) {
        pa[p] = *reinterpret_cast<const float4*>(Aptr + (size_t)(p * 32) * FEAT);
        pb[p] = *reinterpret_cast<const float4*>(Bptr + (size_t)(p * 32) * FEAT);
    }
    const int NK = FEAT / BK;
    for (int kt = 0; kt < NK; ++kt) {
        __syncthreads();
        #pragma unroll
        for (int p = 0; p < 4; ++p) {
            const int r = srow + p * 32;
            ushort4 h, l;
            split4(pa[p], h, l);
            *reinterpret_cast<ushort4*>(&AhS[r][scol]) = h;
            *reinterpret_cast<ushort4*>(&AlS[r][scol]) = l;
            split4(pb[p], h, l);
            *reinterpret_cast<ushort4*>(&BhS[r][scol]) = h;
            *reinterpret_cast<ushort4*>(&BlS[r][scol]) = l;
        }
        __syncthreads();
        if (kt + 1 < NK) {
            const float* An = Aptr + (size_t)(kt + 1) * BK;
            const float* Bn = Bptr + (size_t)(kt + 1) * BK;
            #pragma unroll
            for (int p = 0; p < 4; ++p) {
                pa[p] = *reinterpret_cast<const float4*>(An + (size_t)(p * 32) * FEAT);
                pb[p] = *reinterpret_cast<const float4*>(Bn + (size_t)(p * 32) * FEAT);
            }
        }
        bf16x8 fah[4], fal[4], fbh[4], fbl[4];
        #pragma unroll
        for (int m = 0; m < 4; ++m) {
            fah[m] = *reinterpret_cast<const bf16x8*>(&AhS[wr + m * 16 + fr][fk]);
            fal[m] = *reinterpret_cast<const bf16x8*>(&AlS[wr + m * 16 + fr][fk]);
        }
        #pragma unroll
        for (int n = 0; n < 4; ++n) {
            fbh[n] = *reinterpret_cast<const bf16x8*>(&BhS[wc + n * 16 + fr][fk]);
            fbl[n] = *reinterpret_cast<const bf16x8*>(&BlS[wc + n * 16 + fr][fk]);
        }
        #pragma unroll
        for (int m = 0; m < 4; ++m)
            #pragma unroll
            for (int n = 0; n < 4; ++n) {
                acc[m][n] = __builtin_amdgcn_mfma_f32_16x16x32_bf16(fah[m], fbl[n], acc[m][n], 0, 0, 0);
                acc[m][n] = __builtin_amdgcn_mfma_f32_16x16x32_bf16(fal[m], fbh[n], acc[m][n], 0, 0, 0);
                acc[m][n] = __builtin_amdgcn_mfma_f32_16x16x32_bf16(fah[m], fbh[n], acc[m][n], 0, 0, 0);
            }
    }
    const int orow0 = m0 + wr + (lane >> 4) * 4;
    const int ocol0 = n0 + wc + fr;
    #pragma unroll
    for (int n = 0; n < 4; ++n) {
        const float bv = bias[ocol0 + n * 16];
        #pragma unroll
        for (int m = 0; m < 4; ++m)
            #pragma unroll
            for (int r = 0; r < 4; ++r) {
                float v = acc[m][n][r] + bv;
                out[(size_t)(orow0 + m * 16 + r) * OSTRIDE + (ocol0 + n * 16)] =
                    fmaxf(v, 0.f);
            }
    }
}

// ---------------------------------------------------------------------------
// Inputs: d_in[0] features f32, [1] phrases f32, [2] W f32, [3] b f32,
//         [4] phrase_lengths i32.  Output [B,R,2D] f32.
// ---------------------------------------------------------------------------
extern "C" void kernel_launch(void* const* d_in, const int* in_sizes, int n_in,
                              void* d_out, int out_size, void* d_ws, size_t ws_size,
                              hipStream_t stream) {
    const float* features = (const float*)d_in[0];
    const float* phrases  = (const float*)d_in[1];
    const float* W        = (const float*)d_in[2];
    const float* bias     = (const float*)d_in[3];
    const int*   lengths  = (const int*)d_in[4];
    float* out = (float*)d_out;

    if (ws_size >= WS_NEED) {
        char* ws = (char*)d_ws;
        unsigned short* Ah = (unsigned short*)(ws + WS_AH);
        unsigned short* Al = (unsigned short*)(ws + WS_AL);
        unsigned short* Bh = (unsigned short*)(ws + WS_BH);
        unsigned short* Bl = (unsigned short*)(ws + WS_BL);
        float* pbuf = (float*)(ws + WS_PB);

        split_kernel<<<dim3(2048), dim3(256), 0, stream>>>(
            features, W, Ah, Al, Bh, Bl);
        gemm_mp_kernel<<<dim3(TOTAL_BLOCKS), dim3(256), 0, stream>>>(
            Ah, Al, Bh, Bl, phrases, lengths, pbuf, out);
        epi_kernel<<<dim3(MTOT), dim3(256), 0, stream>>>(pbuf, bias, out);
    } else {
        // ws too small: round-3 verified path
        mean_pool_kernel<<<dim3(MTOT), dim3(256), 0, stream>>>(phrases, lengths, out);
        gemm_relu_mfma<<<dim3(DIM / BN, MTOT / BM), dim3(256), 0, stream>>>(
            features, W, bias, out);
    }
}